// Round 6
// baseline (115.900 us; speedup 1.0000x reference)
//
#include <hip/hip_runtime.h>
#include <hip/hip_bf16.h>

// B=8, C=512, H=W=64, NH=8, HD=64, WIN=64, NW=64.
// Token matrix = x viewed as [32768][512] fp32 (raw reshape).
//   phase 0: convert X -> bf16, W{q,k,v} -> Wcat bf16 [1536][512]
//   phase 1: QKV GEMM M=32768 K=512 N=1536 — 128x128 tile, BK=64, 8 waves,
//            64 KiB LDS -> 2 blocks/CU (cross-block overlap of drains),
//            drift schedule (1 barrier/K-tile), T2 swizzle, coalesced epilogue
//   phase 2: per (window,head): S=Q@K^T(+bias), softmax, P@V
// ws: Wc@0 | Xb@2MiB | Q@36MiB | K@68MiB | V^T@100MiB (132MiB; fits).

typedef __attribute__((ext_vector_type(8))) short bf16x8;
typedef __attribute__((ext_vector_type(4))) float f32x4;

#define GLDS(gp, lp) __builtin_amdgcn_global_load_lds( \
    (const __attribute__((address_space(1))) unsigned int*)(gp), \
    (__attribute__((address_space(3))) unsigned int*)(lp), 16, 0, 0)

__device__ __forceinline__ unsigned short f2bf(float f) {
  union { float f; unsigned int u; } v; v.f = f;
  unsigned int r = v.u + 0x7fffu + ((v.u >> 16) & 1u);  // RNE
  return (unsigned short)(r >> 16);
}

// ---------- prep: X fp32->bf16 and W{q,k,v} -> Wcat bf16 ----------
__global__ __launch_bounds__(256) void prep_convert(
    const float* __restrict__ X, const float* __restrict__ Wq,
    const float* __restrict__ Wk, const float* __restrict__ Wv,
    unsigned short* __restrict__ Xb, unsigned short* __restrict__ Wc) {
  const unsigned int i = blockIdx.x * 256 + threadIdx.x;
  const float* src;
  unsigned short* dst;
  if (i < 2097152u) {                       // X: 16.7M floats, 8 per thread
    src = X + (size_t)i * 8;
    dst = Xb + (size_t)i * 8;
  } else {                                  // Wcat: [1536][512]
    const unsigned int j = i - 2097152u;    // < 98304
    const unsigned int e = j * 8;
    const unsigned int n = e >> 9, kk = e & 511;
    src = ((n < 512) ? Wq : (n < 1024 ? Wk : Wv)) + (size_t)(n & 511) * 512 + kk;
    dst = Wc + (size_t)n * 512 + kk;
  }
  float4 f0 = *(const float4*)(src);
  float4 f1 = *(const float4*)(src + 4);
  __align__(16) unsigned short u[8];
  u[0] = f2bf(f0.x); u[1] = f2bf(f0.y); u[2] = f2bf(f0.z); u[3] = f2bf(f0.w);
  u[4] = f2bf(f1.x); u[5] = f2bf(f1.y); u[6] = f2bf(f1.z); u[7] = f2bf(f1.w);
  *(bf16x8*)(dst) = *(const bf16x8*)(u);
}

// ---------- QKV GEMM: 128x128 tile, BK=64, 8 waves, drift, 2 blocks/CU ----------
// Wave grid 4(M)x2(N): wave tile 32 rows x 64 cols (= half-window x one head).
// LDS 64 KiB: A 2buf x [128][64] bf16 at [0,32K), B same at [32K,64K);
// subtile 16x32 (1 KiB) st_16x32-swizzled exactly as rounds 3-5 (validated).
// Per K-tile: stage all 4 GLDS for t+1 into buf[t^1], plain ds_read+MFMA
// (compiler-scheduled), then vmcnt(0)+one barrier. With 2 blocks/CU the
// drain and epilogue of one block overlap the other block's MFMAs.
__global__ __launch_bounds__(512, 4) void qkv_gemm_128(
    const unsigned short* __restrict__ Xb, const unsigned short* __restrict__ Wc,
    const float* __restrict__ bq, const float* __restrict__ bk,
    const float* __restrict__ bv,
    unsigned short* __restrict__ Qo, unsigned short* __restrict__ Ko,
    unsigned short* __restrict__ Vo) {
  __shared__ __align__(16) char LDS[65536];

  const int tid  = threadIdx.x;
  const int lane = tid & 63;
  const int wid  = tid >> 6;
  const int wm = wid >> 1, wn = wid & 1;    // 4 x 2 wave grid

  // XCD-chunked swizzle: 3072 = 8 x 384 works; n-tiles fastest within chunk.
  const int work = (int)(blockIdx.x & 7) * 384 + (int)(blockIdx.x >> 3);
  const int bx = work % 12, by = work / 12;
  const int n0 = bx * 128, m0 = by * 128;

  // --- staging addressing (linear LDS dest; inverse-swizzled global source) ---
  const int lcol  = ((lane & 3) * 8) ^ ((lane >= 32) ? 16 : 0);   // elements
  const int arow0 = (wid >> 1) * 16 + (lane >> 2);                // 0..63
  const int acol0 = (wid & 1) * 32 + lcol;

#define STAGE_A(tt) do { \
    const unsigned short* g = Xb + (size_t)(m0 + arow0) * 512 + (tt) * 64 + acol0; \
    char* l = LDS + ((tt) & 1) * 16384 + wid * 1024; \
    GLDS(g, l); \
    GLDS(g + 64 * 512, l + 8192); \
  } while (0)

#define STAGE_B(tt) do { \
    const unsigned short* g = Wc + (size_t)(n0 + arow0) * 512 + (tt) * 64 + acol0; \
    char* l = LDS + 32768 + ((tt) & 1) * 16384 + wid * 1024; \
    GLDS(g, l); \
    GLDS(g + 64 * 512, l + 8192); \
  } while (0)

  // --- fragment-read addressing (swizzled; same subtile math as validated) ---
  const int sloff = (((lane & 15) * 64) + ((lane >> 4) * 16)) ^ ((lane & 8) ? 32 : 0);
  char* const Ab = LDS + sloff;
  char* const Bb2 = LDS + 32768 + sloff;

  f32x4 acc[2][4];
#pragma unroll
  for (int i = 0; i < 2; ++i)
#pragma unroll
    for (int j = 0; j < 4; ++j) acc[i][j] = (f32x4){0.f, 0.f, 0.f, 0.f};

  // prologue: stage tile 0 into buf0
  STAGE_A(0); STAGE_B(0);
  asm volatile("s_waitcnt vmcnt(0)" ::: "memory");
  __builtin_amdgcn_s_barrier();

  for (int t = 0; t < 8; ++t) {
    const int bo = (t & 1) * 16384;
    if (t + 1 < 8) { STAGE_A(t + 1); STAGE_B(t + 1); }
    {                                       // full-tile compute, no barriers
      bf16x8 a[2][2], b[4][2];
#pragma unroll
      for (int mi = 0; mi < 2; ++mi)
#pragma unroll
        for (int ks = 0; ks < 2; ++ks)
          a[mi][ks] = *(const bf16x8*)(Ab + bo + (wm * 2 + mi) * 2048 + ks * 1024);
#pragma unroll
      for (int ni = 0; ni < 4; ++ni)
#pragma unroll
        for (int ks = 0; ks < 2; ++ks)
          b[ni][ks] = *(const bf16x8*)(Bb2 + bo + (wn * 4 + ni) * 2048 + ks * 1024);
#pragma unroll
      for (int mi = 0; mi < 2; ++mi)
#pragma unroll
        for (int ni = 0; ni < 4; ++ni)
#pragma unroll
          for (int ks = 0; ks < 2; ++ks)
            acc[mi][ni] = __builtin_amdgcn_mfma_f32_16x16x32_bf16(
                a[mi][ks], b[ni][ks], acc[mi][ni], 0, 0, 0);
    }
    if (t + 1 < 8) asm volatile("s_waitcnt vmcnt(0)" ::: "memory");
    __builtin_amdgcn_s_barrier();
  }

  // ---- epilogue: LDS-staged, coalesced stores ----
  // Wave tile = 32 tokens (half-window) x 64 ch (one head). Per-wave private
  // 4 KiB scratch in the (now dead) A region; chunk-XOR keeps writes ~2-way
  // and b128 reads conflict-free. Q/K: full 128B-row stores; V^T: 64B segs.
  {
    const int p = n0 >> 9;                  // 0:Q 1:K 2:V (tile never spans)
    const float* bias = (p == 0) ? bq : (p == 1) ? bk : bv;
    const float qs = (p == 0) ? 0.125f : 1.0f;
    const int hi = lane >> 4, lr = lane & 15;
    const int h = ((n0 & 511) >> 6) + wn;
    const int r0 = m0 + wm * 32;
    const int win = r0 >> 6;
    const int tw0 = r0 & 63;                // 0 or 32
    char* const scr = LDS + wid * 4096;
    float bsv[4];
#pragma unroll
    for (int ni = 0; ni < 4; ++ni)
      bsv[ni] = bias[(n0 & 511) + wn * 64 + ni * 16 + lr];

    asm volatile("s_waitcnt lgkmcnt(0)" ::: "memory");  // WAR vs K-loop reads
    __builtin_amdgcn_sched_barrier(0);
    if (p < 2) {
      // scr = T[t'][d], t'=0..31, d=0..63; phys col = d ^ ((t'&7)<<3)
#pragma unroll
      for (int mi = 0; mi < 2; ++mi)
#pragma unroll
        for (int ni = 0; ni < 4; ++ni) {
          const int d = ni * 16 + lr;
#pragma unroll
          for (int rr = 0; rr < 4; ++rr) {
            const int tp = mi * 16 + hi * 4 + rr;
            const int off = tp * 64 + (d ^ ((tp & 7) << 3));
            *(unsigned short*)(scr + off * 2) =
                f2bf((acc[mi][ni][rr] + bsv[ni]) * qs);
          }
        }
    } else {
      // scr = T'[d][t'], d=0..63, t'=0..31; phys t-chunk = t0 ^ ((d&3)<<3)
#pragma unroll
      for (int mi = 0; mi < 2; ++mi)
#pragma unroll
        for (int ni = 0; ni < 4; ++ni) {
          const int d = ni * 16 + lr;
          const int t0p = mi * 16 + hi * 4;
          ushort4 pk;
          pk.x = f2bf(acc[mi][ni][0] + bsv[ni]);
          pk.y = f2bf(acc[mi][ni][1] + bsv[ni]);
          pk.z = f2bf(acc[mi][ni][2] + bsv[ni]);
          pk.w = f2bf(acc[mi][ni][3] + bsv[ni]);
          const int off = d * 32 + (t0p ^ ((d & 3) << 3));
          *(ushort4*)(scr + off * 2) = pk;
        }
    }
    asm volatile("s_waitcnt lgkmcnt(0)" ::: "memory");  // writes -> readable
    __builtin_amdgcn_sched_barrier(0);
    unsigned short* dst =
        ((p == 0) ? Qo : (p == 1) ? Ko : Vo) + (size_t)(win * 8 + h) * 4096;
    if (p < 2) {
#pragma unroll
      for (int i = 0; i < 4; ++i) {
        const int r = i * 8 + (lane >> 3);            // 0..31
        const int c = lane & 7;
        const int off = r * 64 + ((c ^ (r & 7)) * 8);
        bf16x8 row = *(const bf16x8*)(scr + off * 2);
        *(bf16x8*)(dst + (size_t)(tw0 + r) * 64 + c * 8) = row;
      }
    } else {
#pragma unroll
      for (int i = 0; i < 4; ++i) {
        const int d = i * 16 + (lane >> 2);           // 0..63
        const int tc = (lane & 3) * 8;
        const int off = d * 32 + (tc ^ ((d & 3) << 3));
        bf16x8 row = *(const bf16x8*)(scr + off * 2);
        *(bf16x8*)(dst + (size_t)d * 64 + tw0 + tc) = row;
      }
    }
  }
#undef STAGE_A
#undef STAGE_B
}

// ---------- attention: 1 wave per (window, head) ----------
__global__ __launch_bounds__(64) void attn_win(
    const unsigned short* __restrict__ Qp, const unsigned short* __restrict__ Kp,
    const unsigned short* __restrict__ Vp, const float* __restrict__ Bb,
    float* __restrict__ out) {
  __shared__ __align__(16) unsigned short P[64 * 72];
  const int lane = threadIdx.x;
  const int win = blockIdx.x >> 3;
  const int h   = blockIdx.x & 7;
  const size_t base = (size_t)(win * 8 + h) * 4096;
  const unsigned short* q = Qp + base;
  const unsigned short* k = Kp + base;
  const unsigned short* v = Vp + base;   // V^T: [d][t]
  const int lr = lane & 15;
  const int hi = lane >> 4;

  bf16x8 qa[4][2], kb[4][2];
#pragma unroll
  for (int mt = 0; mt < 4; ++mt)
#pragma unroll
    for (int ks = 0; ks < 2; ++ks)
      qa[mt][ks] = *(const bf16x8*)(q + (size_t)(mt * 16 + lr) * 64 + ks * 32 + hi * 8);
#pragma unroll
  for (int nt = 0; nt < 4; ++nt)
#pragma unroll
    for (int ks = 0; ks < 2; ++ks)
      kb[nt][ks] = *(const bf16x8*)(k + (size_t)(nt * 16 + lr) * 64 + ks * 32 + hi * 8);

  f32x4 s[4][4];
#pragma unroll
  for (int mt = 0; mt < 4; ++mt)
#pragma unroll
    for (int nt = 0; nt < 4; ++nt) {
      s[mt][nt] = (f32x4){0.f, 0.f, 0.f, 0.f};
      s[mt][nt] = __builtin_amdgcn_mfma_f32_16x16x32_bf16(qa[mt][0], kb[nt][0], s[mt][nt], 0, 0, 0);
      s[mt][nt] = __builtin_amdgcn_mfma_f32_16x16x32_bf16(qa[mt][1], kb[nt][1], s[mt][nt], 0, 0, 0);
    }

#pragma unroll
  for (int mt = 0; mt < 4; ++mt)
#pragma unroll
    for (int nt = 0; nt < 4; ++nt)
#pragma unroll
      for (int rr = 0; rr < 4; ++rr)
        s[mt][nt][rr] += Bb[(mt * 16 + hi * 4 + rr) * 64 + nt * 16 + lr];

  float inv[4][4];
#pragma unroll
  for (int mt = 0; mt < 4; ++mt)
#pragma unroll
    for (int rr = 0; rr < 4; ++rr) {
      float m = fmaxf(fmaxf(s[mt][0][rr], s[mt][1][rr]),
                      fmaxf(s[mt][2][rr], s[mt][3][rr]));
      m = fmaxf(m, __shfl_xor(m, 1));
      m = fmaxf(m, __shfl_xor(m, 2));
      m = fmaxf(m, __shfl_xor(m, 4));
      m = fmaxf(m, __shfl_xor(m, 8));
      float sum = 0.f;
#pragma unroll
      for (int nt = 0; nt < 4; ++nt) {
        float e = __expf(s[mt][nt][rr] - m);
        s[mt][nt][rr] = e;
        sum += e;
      }
      sum += __shfl_xor(sum, 1);
      sum += __shfl_xor(sum, 2);
      sum += __shfl_xor(sum, 4);
      sum += __shfl_xor(sum, 8);
      inv[mt][rr] = 1.0f / sum;
    }

#pragma unroll
  for (int mt = 0; mt < 4; ++mt)
#pragma unroll
    for (int nt = 0; nt < 4; ++nt)
#pragma unroll
      for (int rr = 0; rr < 4; ++rr)
        P[(mt * 16 + hi * 4 + rr) * 72 + nt * 16 + lr] =
            f2bf(s[mt][nt][rr] * inv[mt][rr]);
  __syncthreads();

  bf16x8 pa[4][2], vb[4][2];
#pragma unroll
  for (int mt = 0; mt < 4; ++mt)
#pragma unroll
    for (int ks = 0; ks < 2; ++ks)
      pa[mt][ks] = *(const bf16x8*)(&P[(mt * 16 + lr) * 72 + ks * 32 + hi * 8]);
#pragma unroll
  for (int nt = 0; nt < 4; ++nt)
#pragma unroll
    for (int ks = 0; ks < 2; ++ks)
      vb[nt][ks] = *(const bf16x8*)(v + (size_t)(nt * 16 + lr) * 64 + ks * 32 + hi * 8);

  f32x4 o[4][4];
#pragma unroll
  for (int mt = 0; mt < 4; ++mt)
#pragma unroll
    for (int nt = 0; nt < 4; ++nt) {
      o[mt][nt] = (f32x4){0.f, 0.f, 0.f, 0.f};
      o[mt][nt] = __builtin_amdgcn_mfma_f32_16x16x32_bf16(pa[mt][0], vb[nt][0], o[mt][nt], 0, 0, 0);
      o[mt][nt] = __builtin_amdgcn_mfma_f32_16x16x32_bf16(pa[mt][1], vb[nt][1], o[mt][nt], 0, 0, 0);
    }

  float* op = out + (size_t)win * 32768 + h * 64;
#pragma unroll
  for (int mt = 0; mt < 4; ++mt)
#pragma unroll
    for (int nt = 0; nt < 4; ++nt)
#pragma unroll
      for (int rr = 0; rr < 4; ++rr)
        op[(size_t)(mt * 16 + hi * 4 + rr) * 512 + nt * 16 + lr] = o[mt][nt][rr];
}

extern "C" void kernel_launch(void* const* d_in, const int* in_sizes, int n_in,
                              void* d_out, int out_size, void* d_ws, size_t ws_size,
                              hipStream_t stream) {
  const float* x     = (const float*)d_in[0];
  const float* Wq    = (const float*)d_in[1];
  const float* bq    = (const float*)d_in[2];
  const float* Wk    = (const float*)d_in[3];
  const float* bk    = (const float*)d_in[4];
  const float* Wv    = (const float*)d_in[5];
  const float* bv    = (const float*)d_in[6];
  const float* Bbias = (const float*)d_in[7];
  float* out = (float*)d_out;

  // ws: Wc@0 | Xb@2MiB | Q@36MiB | K@68MiB | V^T@100MiB
  unsigned short* Wc = (unsigned short*)d_ws;
  unsigned short* Xb = (unsigned short*)((char*)d_ws + ((size_t)2 << 20));
  unsigned short* Q  = (unsigned short*)((char*)d_ws + ((size_t)36 << 20));
  unsigned short* K  = (unsigned short*)((char*)d_ws + ((size_t)68 << 20));
  unsigned short* V  = (unsigned short*)((char*)d_ws + ((size_t)100 << 20));

  prep_convert<<<dim3(8576), dim3(256), 0, stream>>>(x, Wq, Wk, Wv, Xb, Wc);
  qkv_gemm_128<<<dim3(3072), dim3(512), 0, stream>>>(Xb, Wc, bq, bk, bv, Q, K, V);
  attn_win<<<dim3(4096), dim3(64), 0, stream>>>(Q, K, V, Bbias, out);
}

// Round 7
// 112.264 us; speedup vs baseline: 1.0324x; 1.0324x over previous
//
#include <hip/hip_runtime.h>
#include <hip/hip_bf16.h>

// B=8, C=512, H=W=64, NH=8, HD=64, WIN=64, NW=64.
// Token matrix = x viewed as [32768][512] fp32 (raw reshape).
//   phase 0: convert X -> bf16, W{q,k,v} -> Wcat bf16 (hw cvt_pk, not manual)
//   phase 1: QKV GEMM M=32768 K=512 N=1536 — 256x256 tile, BK=64, 8 waves,
//            drift schedule (1 barrier/K-tile) + half-K fragment register
//            double-buffer: ks=1 reads issue under ks=0 MFMA cluster.
//   phase 2: per (window,head): S=Q@K^T(+bias), softmax, P@V
// ws: Wc@0 | Xb@2MiB | Q@36MiB | K@68MiB | V^T@100MiB (132MiB; fits).

typedef __attribute__((ext_vector_type(8))) short bf16x8;
typedef __attribute__((ext_vector_type(4))) float f32x4;

#define GLDS(gp, lp) __builtin_amdgcn_global_load_lds( \
    (const __attribute__((address_space(1))) unsigned int*)(gp), \
    (__attribute__((address_space(3))) unsigned int*)(lp), 16, 0, 0)

__device__ __forceinline__ unsigned short f2bf(float f) {
  union { __hip_bfloat16 h; unsigned short u; } v;
  v.h = __float2bfloat16(f);               // lowers to v_cvt_pk_bf16_f32 (RNE)
  return v.u;
}

// ---------- prep: X fp32->bf16 and W{q,k,v} -> Wcat bf16 ----------
__global__ __launch_bounds__(256) void prep_convert(
    const float* __restrict__ X, const float* __restrict__ Wq,
    const float* __restrict__ Wk, const float* __restrict__ Wv,
    unsigned short* __restrict__ Xb, unsigned short* __restrict__ Wc) {
  const unsigned int i = blockIdx.x * 256 + threadIdx.x;
  const float* src;
  unsigned short* dst;
  if (i < 2097152u) {                       // X: 16.7M floats, 8 per thread
    src = X + (size_t)i * 8;
    dst = Xb + (size_t)i * 8;
  } else {                                  // Wcat: [1536][512]
    const unsigned int j = i - 2097152u;    // < 98304
    const unsigned int e = j * 8;
    const unsigned int n = e >> 9, kk = e & 511;
    src = ((n < 512) ? Wq : (n < 1024 ? Wk : Wv)) + (size_t)(n & 511) * 512 + kk;
    dst = Wc + (size_t)n * 512 + kk;
  }
  float4 f0 = *(const float4*)(src);
  float4 f1 = *(const float4*)(src + 4);
  __align__(16) unsigned short u[8];
  u[0] = f2bf(f0.x); u[1] = f2bf(f0.y); u[2] = f2bf(f0.z); u[3] = f2bf(f0.w);
  u[4] = f2bf(f1.x); u[5] = f2bf(f1.y); u[6] = f2bf(f1.z); u[7] = f2bf(f1.w);
  *(bf16x8*)(dst) = *(const bf16x8*)(u);
}

// ---------- QKV GEMM: 256x256 tile, BK=64, 8 waves, pipelined drift ----------
// LDS 128KiB (r3-validated layout): A 2buf x 2Mhalf x [128][64] bf16 subtiled
// 16x32 st_16x32-swizzled at [0,64K); B same at [64K,128K).
// Per K-tile: stage tile t+1 (8 GLDS into buf[t^1]); issue ks=1 frag reads;
// MFMA ks=0 (reads land underneath); MFMA ks=1; vmcnt(0)+barrier; read ks=0
// of tile t+1. One barrier per tile; LDS bursts overlap MFMA bursts.
__global__ __launch_bounds__(512, 2) void qkv_gemm_256(
    const unsigned short* __restrict__ Xb, const unsigned short* __restrict__ Wc,
    const float* __restrict__ bq, const float* __restrict__ bk,
    const float* __restrict__ bv,
    unsigned short* __restrict__ Qo, unsigned short* __restrict__ Ko,
    unsigned short* __restrict__ Vo) {
  __shared__ __align__(16) char LDS[131072];

  const int tid  = threadIdx.x;
  const int lane = tid & 63;
  const int wid  = tid >> 6;
  const int wm = wid >> 2, wn = wid & 3;   // 2(M) x 4(N); wave tile 128x64

  // XCD-chunked swizzle: 768 = 8 x 96 works; n-tiles fastest within a chunk.
  const int work = (int)(blockIdx.x & 7) * 96 + (int)(blockIdx.x >> 3);
  const int bx = work % 6, by = work / 6;
  const int n0 = bx * 256, m0 = by * 256;

  // --- staging addressing (linear LDS dest; inverse-swizzled global source) ---
  const int lcol  = ((lane & 3) * 8) ^ ((lane >= 32) ? 16 : 0);   // elements
  const int arow0 = (wid >> 1) * 16 + (lane >> 2);                // 0..63
  const int acol0 = (wid & 1) * 32 + lcol;

#define STAGE_A(half, tt) do { \
    const unsigned short* g = Xb + (size_t)(m0 + (half) * 128 + arow0) * 512 + (tt) * 64 + acol0; \
    char* l = LDS + ((tt) & 1) * 32768 + (half) * 16384 + wid * 1024; \
    GLDS(g, l); \
    GLDS(g + 64 * 512, l + 8192); \
  } while (0)

#define STAGE_B(half, tt) do { \
    const unsigned short* g = Wc + (size_t)(n0 + (half) * 128 + arow0) * 512 + (tt) * 64 + acol0; \
    char* l = LDS + 65536 + ((tt) & 1) * 32768 + (half) * 16384 + wid * 1024; \
    GLDS(g, l); \
    GLDS(g + 64 * 512, l + 8192); \
  } while (0)

  // --- fragment-read addressing (swizzled; validated r3-r5) ---
  const int sloff = (((lane & 15) * 64) + ((lane >> 4) * 16)) ^ ((lane & 8) ? 32 : 0);
  char* const Ab = LDS + wm * 16384 + sloff;
  char* const Bb2 = LDS + 65536 + (wn >> 1) * 16384 + sloff;
  const int bfr = (wn & 1) * 4;   // B frag index base within half

  f32x4 acc[8][4];
#pragma unroll
  for (int i = 0; i < 8; ++i)
#pragma unroll
    for (int j = 0; j < 4; ++j) acc[i][j] = (f32x4){0.f, 0.f, 0.f, 0.f};

#define RD_A(dst, ks, bo) do { \
    _Pragma("unroll") for (int mi = 0; mi < 8; ++mi) \
      dst[mi] = *(const bf16x8*)(Ab + (bo) + mi * 2048 + (ks) * 1024); \
  } while (0)

#define RD_B(dst, ks, bo) do { \
    _Pragma("unroll") for (int ni = 0; ni < 4; ++ni) \
      dst[ni] = *(const bf16x8*)(Bb2 + (bo) + (bfr + ni) * 2048 + (ks) * 1024); \
  } while (0)

#define MMH(aa, bb) do { \
    _Pragma("unroll") for (int mi = 0; mi < 8; ++mi) \
    _Pragma("unroll") for (int ni = 0; ni < 4; ++ni) \
      acc[mi][ni] = __builtin_amdgcn_mfma_f32_16x16x32_bf16( \
          aa[mi], bb[ni], acc[mi][ni], 0, 0, 0); \
  } while (0)

  // prologue: stage tile 0 into buf0, read its ks=0 fragments
  STAGE_A(0, 0); STAGE_A(1, 0); STAGE_B(0, 0); STAGE_B(1, 0);
  asm volatile("s_waitcnt vmcnt(0)" ::: "memory");
  __builtin_amdgcn_s_barrier();

  bf16x8 aP[8], bP[4], aQ[8], bQ[4];
  RD_A(aP, 0, 0); RD_B(bP, 0, 0);

  for (int t = 0; t < 8; ++t) {
    const int bo = (t & 1) * 32768;
    if (t + 1 < 8) {                        // stage next tile into free buffer
      STAGE_A(0, t + 1); STAGE_A(1, t + 1);
      STAGE_B(0, t + 1); STAGE_B(1, t + 1);
    }
    RD_A(aQ, 1, bo); RD_B(bQ, 1, bo);       // ks=1 reads land under ks=0 MFMAs
    MMH(aP, bP);                            // ks=0: 32 MFMA, no wait needed
    MMH(aQ, bQ);                            // ks=1: compiler lgkm-waits
    if (t + 1 < 8) asm volatile("s_waitcnt vmcnt(0)" ::: "memory");
    __builtin_amdgcn_s_barrier();
    if (t + 1 < 8) { RD_A(aP, 0, bo ^ 32768); RD_B(bP, 0, bo ^ 32768); }
  }

  // ---- epilogue: LDS-staged, coalesced 16B stores (validated r4-r5) ----
  {
    const int p = n0 >> 9;                  // 0:Q 1:K 2:V (256-tile never spans)
    const float* bias = (p == 0) ? bq : (p == 1) ? bk : bv;
    const float qs = (p == 0) ? 0.125f : 1.0f;
    const int hi = lane >> 4, lr = lane & 15;
    const int h = ((n0 & 511) + wn * 64) >> 6;
    char* const scr = LDS + wid * 8192;
    float bsv[4];
#pragma unroll
    for (int ni = 0; ni < 4; ++ni)
      bsv[ni] = bias[(n0 & 511) + wn * 64 + ni * 16 + lr];

#pragma unroll
    for (int wh = 0; wh < 2; ++wh) {
      asm volatile("s_waitcnt lgkmcnt(0)" ::: "memory");  // WAR vs prev reads
      __builtin_amdgcn_sched_barrier(0);
      if (p < 2) {
        // T[t][d]: thread writes (t = f*16+hi*4+rr, d = ni*16+lr)
#pragma unroll
        for (int f = 0; f < 4; ++f)
#pragma unroll
          for (int ni = 0; ni < 4; ++ni) {
            const int d = ni * 16 + lr;
#pragma unroll
            for (int rr = 0; rr < 4; ++rr) {
              const int t = f * 16 + hi * 4 + rr;
              const int off = t * 64 + (d ^ ((t & 7) << 3));
              *(unsigned short*)(scr + off * 2) =
                  f2bf((acc[wh * 4 + f][ni][rr] + bsv[ni]) * qs);
            }
          }
      } else {
        // T'[d][t]: thread packs 4 consecutive t (rr) at fixed d -> b64
#pragma unroll
        for (int f = 0; f < 4; ++f)
#pragma unroll
          for (int ni = 0; ni < 4; ++ni) {
            const int d = ni * 16 + lr;
            const int t0 = f * 16 + hi * 4;
            ushort4 pk;
            pk.x = f2bf(acc[wh * 4 + f][ni][0] + bsv[ni]);
            pk.y = f2bf(acc[wh * 4 + f][ni][1] + bsv[ni]);
            pk.z = f2bf(acc[wh * 4 + f][ni][2] + bsv[ni]);
            pk.w = f2bf(acc[wh * 4 + f][ni][3] + bsv[ni]);
            const int off = d * 64 + (t0 ^ ((d & 7) << 3));
            *(ushort4*)(scr + off * 2) = pk;
          }
      }
      asm volatile("s_waitcnt lgkmcnt(0)" ::: "memory");  // writes -> readable
      __builtin_amdgcn_sched_barrier(0);
      const int win = (m0 + wm * 128 + wh * 64) >> 6;
      unsigned short* dst =
          ((p == 0) ? Qo : (p == 1) ? Ko : Vo) + (size_t)(win * 8 + h) * 4096;
#pragma unroll
      for (int i = 0; i < 8; ++i) {
        const int r = i * 8 + (lane >> 3);
        const int c = lane & 7;
        const int off = r * 64 + ((c ^ (r & 7)) * 8);
        bf16x8 row = *(const bf16x8*)(scr + off * 2);   // ds_read_b128
        *(bf16x8*)(dst + r * 64 + c * 8) = row;         // coalesced 16B store
      }
    }
  }
#undef STAGE_A
#undef STAGE_B
#undef RD_A
#undef RD_B
#undef MMH
}

// ---------- attention: 1 wave per (window, head) ----------
__global__ __launch_bounds__(64) void attn_win(
    const unsigned short* __restrict__ Qp, const unsigned short* __restrict__ Kp,
    const unsigned short* __restrict__ Vp, const float* __restrict__ Bb,
    float* __restrict__ out) {
  __shared__ __align__(16) unsigned short P[64 * 72];
  const int lane = threadIdx.x;
  const int win = blockIdx.x >> 3;
  const int h   = blockIdx.x & 7;
  const size_t base = (size_t)(win * 8 + h) * 4096;
  const unsigned short* q = Qp + base;
  const unsigned short* k = Kp + base;
  const unsigned short* v = Vp + base;   // V^T: [d][t]
  const int lr = lane & 15;
  const int hi = lane >> 4;

  bf16x8 qa[4][2], kb[4][2];
#pragma unroll
  for (int mt = 0; mt < 4; ++mt)
#pragma unroll
    for (int ks = 0; ks < 2; ++ks)
      qa[mt][ks] = *(const bf16x8*)(q + (size_t)(mt * 16 + lr) * 64 + ks * 32 + hi * 8);
#pragma unroll
  for (int nt = 0; nt < 4; ++nt)
#pragma unroll
    for (int ks = 0; ks < 2; ++ks)
      kb[nt][ks] = *(const bf16x8*)(k + (size_t)(nt * 16 + lr) * 64 + ks * 32 + hi * 8);

  f32x4 s[4][4];
#pragma unroll
  for (int mt = 0; mt < 4; ++mt)
#pragma unroll
    for (int nt = 0; nt < 4; ++nt) {
      s[mt][nt] = (f32x4){0.f, 0.f, 0.f, 0.f};
      s[mt][nt] = __builtin_amdgcn_mfma_f32_16x16x32_bf16(qa[mt][0], kb[nt][0], s[mt][nt], 0, 0, 0);
      s[mt][nt] = __builtin_amdgcn_mfma_f32_16x16x32_bf16(qa[mt][1], kb[nt][1], s[mt][nt], 0, 0, 0);
    }

#pragma unroll
  for (int mt = 0; mt < 4; ++mt)
#pragma unroll
    for (int nt = 0; nt < 4; ++nt)
#pragma unroll
      for (int rr = 0; rr < 4; ++rr)
        s[mt][nt][rr] += Bb[(mt * 16 + hi * 4 + rr) * 64 + nt * 16 + lr];

  float inv[4][4];
#pragma unroll
  for (int mt = 0; mt < 4; ++mt)
#pragma unroll
    for (int rr = 0; rr < 4; ++rr) {
      float m = fmaxf(fmaxf(s[mt][0][rr], s[mt][1][rr]),
                      fmaxf(s[mt][2][rr], s[mt][3][rr]));
      m = fmaxf(m, __shfl_xor(m, 1));
      m = fmaxf(m, __shfl_xor(m, 2));
      m = fmaxf(m, __shfl_xor(m, 4));
      m = fmaxf(m, __shfl_xor(m, 8));
      float sum = 0.f;
#pragma unroll
      for (int nt = 0; nt < 4; ++nt) {
        float e = __expf(s[mt][nt][rr] - m);
        s[mt][nt][rr] = e;
        sum += e;
      }
      sum += __shfl_xor(sum, 1);
      sum += __shfl_xor(sum, 2);
      sum += __shfl_xor(sum, 4);
      sum += __shfl_xor(sum, 8);
      inv[mt][rr] = 1.0f / sum;
    }

#pragma unroll
  for (int mt = 0; mt < 4; ++mt)
#pragma unroll
    for (int nt = 0; nt < 4; ++nt)
#pragma unroll
      for (int rr = 0; rr < 4; ++rr)
        P[(mt * 16 + hi * 4 + rr) * 72 + nt * 16 + lr] =
            f2bf(s[mt][nt][rr] * inv[mt][rr]);
  __syncthreads();

  bf16x8 pa[4][2], vb[4][2];
#pragma unroll
  for (int mt = 0; mt < 4; ++mt)
#pragma unroll
    for (int ks = 0; ks < 2; ++ks)
      pa[mt][ks] = *(const bf16x8*)(&P[(mt * 16 + lr) * 72 + ks * 32 + hi * 8]);
#pragma unroll
  for (int nt = 0; nt < 4; ++nt)
#pragma unroll
    for (int ks = 0; ks < 2; ++ks)
      vb[nt][ks] = *(const bf16x8*)(v + (size_t)(nt * 16 + lr) * 64 + ks * 32 + hi * 8);

  f32x4 o[4][4];
#pragma unroll
  for (int mt = 0; mt < 4; ++mt)
#pragma unroll
    for (int nt = 0; nt < 4; ++nt) {
      o[mt][nt] = (f32x4){0.f, 0.f, 0.f, 0.f};
      o[mt][nt] = __builtin_amdgcn_mfma_f32_16x16x32_bf16(pa[mt][0], vb[nt][0], o[mt][nt], 0, 0, 0);
      o[mt][nt] = __builtin_amdgcn_mfma_f32_16x16x32_bf16(pa[mt][1], vb[nt][1], o[mt][nt], 0, 0, 0);
    }

  float* op = out + (size_t)win * 32768 + h * 64;
#pragma unroll
  for (int mt = 0; mt < 4; ++mt)
#pragma unroll
    for (int nt = 0; nt < 4; ++nt)
#pragma unroll
      for (int rr = 0; rr < 4; ++rr)
        op[(size_t)(mt * 16 + hi * 4 + rr) * 512 + nt * 16 + lr] = o[mt][nt][rr];
}

extern "C" void kernel_launch(void* const* d_in, const int* in_sizes, int n_in,
                              void* d_out, int out_size, void* d_ws, size_t ws_size,
                              hipStream_t stream) {
  const float* x     = (const float*)d_in[0];
  const float* Wq    = (const float*)d_in[1];
  const float* bq    = (const float*)d_in[2];
  const float* Wk    = (const float*)d_in[3];
  const float* bk    = (const float*)d_in[4];
  const float* Wv    = (const float*)d_in[5];
  const float* bv    = (const float*)d_in[6];
  const float* Bbias = (const float*)d_in[7];
  float* out = (float*)d_out;

  // ws: Wc@0 | Xb@2MiB | Q@36MiB | K@68MiB | V^T@100MiB
  unsigned short* Wc = (unsigned short*)d_ws;
  unsigned short* Xb = (unsigned short*)((char*)d_ws + ((size_t)2 << 20));
  unsigned short* Q  = (unsigned short*)((char*)d_ws + ((size_t)36 << 20));
  unsigned short* K  = (unsigned short*)((char*)d_ws + ((size_t)68 << 20));
  unsigned short* V  = (unsigned short*)((char*)d_ws + ((size_t)100 << 20));

  prep_convert<<<dim3(8576), dim3(256), 0, stream>>>(x, Wq, Wk, Wv, Xb, Wc);
  qkv_gemm_256<<<dim3(768), dim3(512), 0, stream>>>(Xb, Wc, bq, bk, bv, Q, K, V);
  attn_win<<<dim3(4096), dim3(64), 0, stream>>>(Q, K, V, Bbias, out);
}